// Round 7
// baseline (3051.712 us; speedup 1.0000x reference)
//
#include <hip/hip_runtime.h>
#include <stdint.h>
#include <stddef.h>

#define B_   16
#define T_   256
#define L_   1024
#define H_   1024
#define G3_  3072
#define KIN_ 96

// NaN bf16 pattern: can never be produced by the GRU (|h| <= 1, finite arithmetic)
#define SENT_     0x7FC1
#define SENT_X2_  0x7FC17FC1u

typedef __attribute__((ext_vector_type(8))) __bf16 bf16x8;
typedef __attribute__((ext_vector_type(4))) float  f32x4;
typedef __attribute__((ext_vector_type(4))) int    i32x4;

static __device__ __forceinline__ unsigned short f2bf(float x) {
  unsigned int u = __builtin_bit_cast(unsigned int, x);
  u += 0x7FFFu + ((u >> 16) & 1u);           // RNE
  return (unsigned short)(u >> 16);
}
static __device__ __forceinline__ float bf2f(unsigned short s) {
  unsigned int u = ((unsigned int)s) << 16;
  return __builtin_bit_cast(float, u);
}
// nonzero iff either 16-bit half of d equals the sentinel (exact SWAR detector)
static __device__ __forceinline__ unsigned sentmask(unsigned d) {
  const unsigned x = d ^ SENT_X2_;
  return (x - 0x00010001u) & ~x & 0x80008000u;
}

// ---------------------------------------------------------------- prep
// One fused kernel, plain stores (end-of-kernel L2 writeback publishes them):
// bf16 converts, lateral transpose, sentinel fills of hs + mirror, h0 zeros,
// attention-ones output, claim-array zero.
__global__ void prep_kernel(
    const float* __restrict__ whh,  unsigned short* __restrict__ whh_bf,
    const float* __restrict__ wih,  unsigned short* __restrict__ wih_bf,
    const float* __restrict__ fiw1, unsigned short* __restrict__ fiw1_bf,
    const float* __restrict__ fiw2, unsigned short* __restrict__ fiw2_bf,
    const float* __restrict__ lat,  unsigned short* __restrict__ latT_bf,
    unsigned short* __restrict__ hsbuf, unsigned short* __restrict__ hmbuf,
    float* __restrict__ attn_out, int* __restrict__ claim) {
  const int N0 = G3_ * H_;
  const int N1 = N0 + G3_ * KIN_;
  const int N2 = N1 + H_ * H_;
  const int N3 = N2 + H_ * H_;
  const int N4 = N3 + H_ * H_;             // lat transpose
  const int N5 = N4 + T_ * B_ * H_ / 2;    // hs sentinel (dword units)
  const int N6 = N5 + B_ * H_ / 2;         // hs h0 zero
  const int N7 = N6 + B_ * T_;             // attention ones
  const int N8 = N7 + 16;                  // claim zero
  const int N9 = N8 + T_ * B_ * H_ / 2;    // mirror sentinel
  const int N10 = N9 + B_ * H_ / 2;        // mirror h0 zero
  int i = blockIdx.x * 256 + threadIdx.x;
  const int stride = gridDim.x * 256;
  unsigned int* hs32 = (unsigned int*)hsbuf;
  unsigned int* hm32 = (unsigned int*)hmbuf;
  for (; i < N10; i += stride) {
    if (i < N0)      whh_bf[i] = f2bf(whh[i]);
    else if (i < N1) { const int j = i - N0; wih_bf[j]  = f2bf(wih[j]); }
    else if (i < N2) { const int j = i - N1; fiw1_bf[j] = f2bf(fiw1[j]); }
    else if (i < N3) { const int j = i - N2; fiw2_bf[j] = f2bf(fiw2[j]); }
    else if (i < N4) { const int j = i - N3; const int r = j >> 10, c = j & 1023;
                       latT_bf[(size_t)c * H_ + r] = f2bf(lat[j]); }
    else if (i < N5) { hs32[B_ * H_ / 2 + (i - N4)] = SENT_X2_; }
    else if (i < N6) { hs32[i - N5] = 0u; }
    else if (i < N7) { attn_out[i - N6] = 1.0f; }
    else if (i < N8) { claim[i - N7] = 0; }
    else if (i < N9) { hm32[B_ * H_ / 2 + (i - N8)] = SENT_X2_; }
    else             { hm32[i - N9] = 0u; }
  }
}

// ---------------------------------------------------------------- conv+pool
__global__ __launch_bounds__(256) void conv_kernel(
    const float* __restrict__ x,
    const float* __restrict__ w3, const float* __restrict__ b3,
    const float* __restrict__ w5, const float* __restrict__ b5,
    const float* __restrict__ w7, const float* __restrict__ b7,
    unsigned short* __restrict__ feat) {
  __shared__ float xpad[L_ + 8];
  __shared__ float wlds[96][8];
  __shared__ float blds[96];
  __shared__ float wmax[4][96];
  const int tid = threadIdx.x;
  const int rid = blockIdx.x;          // b*T + t
  const int b = rid >> 8;
  const int t = rid & 255;
  const float* xr = x + (size_t)rid * L_;
  for (int off = tid; off < L_; off += 256) xpad[off + 3] = xr[off];
  if (tid < 3) xpad[tid] = 0.f;
  if (tid >= 3 && tid < 8) xpad[L_ + tid] = 0.f;
  if (tid < 96) {
    const int f = tid;
    float wv[8];
#pragma unroll
    for (int k = 0; k < 8; ++k) wv[k] = 0.f;
    float bv;
    if (f < 32)      { for (int k = 0; k < 3; ++k) wv[k + 2] = w3[f * 3 + k]; bv = b3[f]; }
    else if (f < 64) { int ff = f - 32; for (int k = 0; k < 5; ++k) wv[k + 1] = w5[ff * 5 + k]; bv = b5[ff]; }
    else             { int ff = f - 64; for (int k = 0; k < 7; ++k) wv[k] = w7[ff * 7 + k]; bv = b7[ff]; }
#pragma unroll
    for (int k = 0; k < 8; ++k) wlds[f][k] = wv[k];
    blds[f] = bv;
  }
  __syncthreads();
  const int w = tid >> 6, lane = tid & 63;
  const int p0 = w * 256 + lane * 4;
  float xv[10];
#pragma unroll
  for (int i = 0; i < 10; ++i) xv[i] = xpad[p0 + i];
  for (int f = 0; f < 96; ++f) {
    float a0 = 0.f, a1 = 0.f, a2 = 0.f, a3 = 0.f;
#pragma unroll
    for (int k = 0; k < 7; ++k) {
      const float wk = wlds[f][k];
      a0 = fmaf(wk, xv[k],     a0);
      a1 = fmaf(wk, xv[k + 1], a1);
      a2 = fmaf(wk, xv[k + 2], a2);
      a3 = fmaf(wk, xv[k + 3], a3);
    }
    float m = fmaxf(fmaxf(a0, a1), fmaxf(a2, a3));
#pragma unroll
    for (int d = 1; d < 64; d <<= 1) m = fmaxf(m, __shfl_xor(m, d, 64));
    if (lane == 0) wmax[w][f] = m;
  }
  __syncthreads();
  if (tid < 96) {
    float m = fmaxf(fmaxf(wmax[0][tid], wmax[1][tid]),
                    fmaxf(wmax[2][tid], wmax[3][tid]));
    m += blds[tid];
    m = m > 0.f ? m : 0.f;
    feat[(size_t)(t * B_ + b) * KIN_ + tid] = f2bf(m);   // row = t*B + b
  }
}

// ---------------------------------------------------------------- GEMM
// C[M,N] = A[M,K] * B[N,K]^T  (both bf16, row-major). 128x128 tile, BK=32,
// 4 waves, double-buffered LDS, padded stride 40.
template <int EP>
__global__ __launch_bounds__(256) void gemm_kernel(
    const unsigned short* __restrict__ A,
    const unsigned short* __restrict__ Bm,
    int M, int N, int K, int lda, int ldb,
    const float* __restrict__ bias,
    float* __restrict__ outF,
    unsigned short* __restrict__ outB) {
  __shared__ __align__(16) unsigned short As[2][128 * 40];
  __shared__ __align__(16) unsigned short Bs[2][128 * 40];
  const int tid = threadIdx.x;
  const int n0 = blockIdx.x * 128;
  const int m0 = blockIdx.y * 128;
  const int w = tid >> 6;
  const int l = tid & 63;
  const int lr = l & 15;
  const int lk = (l >> 4) * 8;
  const int srow = tid >> 2;
  const int skc = (tid & 3) * 8;

  f32x4 acc[2][8];
#pragma unroll
  for (int i = 0; i < 2; ++i)
#pragma unroll
    for (int j = 0; j < 8; ++j) acc[i][j] = (f32x4){0.f, 0.f, 0.f, 0.f};

  const int NK = K >> 5;
  const unsigned short* Aptr  = A  + (size_t)(m0 + srow)      * lda + skc;
  const unsigned short* Aptr2 = A  + (size_t)(m0 + 64 + srow) * lda + skc;
  const unsigned short* Bptr  = Bm + (size_t)(n0 + srow)      * ldb + skc;
  const unsigned short* Bptr2 = Bm + (size_t)(n0 + 64 + srow) * ldb + skc;

  i32x4 ar0 = *(const i32x4*)(Aptr);
  i32x4 ar1 = *(const i32x4*)(Aptr2);
  i32x4 br0 = *(const i32x4*)(Bptr);
  i32x4 br1 = *(const i32x4*)(Bptr2);
  *(i32x4*)&As[0][srow * 40 + skc]        = ar0;
  *(i32x4*)&As[0][(64 + srow) * 40 + skc] = ar1;
  *(i32x4*)&Bs[0][srow * 40 + skc]        = br0;
  *(i32x4*)&Bs[0][(64 + srow) * 40 + skc] = br1;
  __syncthreads();

  for (int kk = 0; kk < NK; ++kk) {
    const int cur = kk & 1;
    if (kk + 1 < NK) {
      const int ko = (kk + 1) << 5;
      ar0 = *(const i32x4*)(Aptr  + ko);
      ar1 = *(const i32x4*)(Aptr2 + ko);
      br0 = *(const i32x4*)(Bptr  + ko);
      br1 = *(const i32x4*)(Bptr2 + ko);
    }
    const bf16x8 a0 = *(const bf16x8*)&As[cur][(w * 32 + lr) * 40 + lk];
    const bf16x8 a1 = *(const bf16x8*)&As[cur][(w * 32 + 16 + lr) * 40 + lk];
#pragma unroll
    for (int nt = 0; nt < 8; ++nt) {
      const bf16x8 bb = *(const bf16x8*)&Bs[cur][(nt * 16 + lr) * 40 + lk];
      acc[0][nt] = __builtin_amdgcn_mfma_f32_16x16x32_bf16(a0, bb, acc[0][nt], 0, 0, 0);
      acc[1][nt] = __builtin_amdgcn_mfma_f32_16x16x32_bf16(a1, bb, acc[1][nt], 0, 0, 0);
    }
    __syncthreads();
    if (kk + 1 < NK) {
      const int nxt = cur ^ 1;
      *(i32x4*)&As[nxt][srow * 40 + skc]        = ar0;
      *(i32x4*)&As[nxt][(64 + srow) * 40 + skc] = ar1;
      *(i32x4*)&Bs[nxt][srow * 40 + skc]        = br0;
      *(i32x4*)&Bs[nxt][(64 + srow) * 40 + skc] = br1;
    }
    __syncthreads();
  }

#pragma unroll
  for (int mt = 0; mt < 2; ++mt) {
#pragma unroll
    for (int nt = 0; nt < 8; ++nt) {
      const f32x4 v = acc[mt][nt];
      const int gcol = n0 + nt * 16 + lr;
#pragma unroll
      for (int e = 0; e < 4; ++e) {
        const int grow = m0 + w * 32 + mt * 16 + (l >> 4) * 4 + e;
        const float val = v[e];
        if (EP == 0) {
          outF[(size_t)grow * N + gcol] = val + bias[gcol];
        } else if (EP == 1) {
          const float hsv = bf2f(A[(size_t)grow * lda + gcol]);
          outB[(size_t)grow * N + gcol] = f2bf(hsv - fmaxf(val, 0.f));
        } else if (EP == 2) {
          outB[(size_t)grow * N + gcol] = f2bf(fmaxf(val + bias[gcol], 0.f));
        } else {
          const int tt = grow >> 4;   // row = t*B + b
          const int bb2 = grow & 15;
          outF[((size_t)bb2 * T_ + tt) * H_ + gcol] = val + bias[gcol];
        }
      }
    }
  }
}

// ---------------------------------------------------------------- GRU scan
// XCD-confined persistent dataflow, no-spill geometry (round-4 proven:
// 16 cols/WG, af[3][4]=48 VGPRs). 2048 WGs x 512 thr launched.
// Claim: winner = first XCD to 24 claims (pigeonhole-safe at >=1 WG/CU);
// workers = first 64 claimants on the winner XCD (grid backfill guarantees
// they materialize; 52 KB LDS allows 2-3 WG/CU so typically immediate).
// Data path: producers store h TWICE — primary sc0 (same-XCD L2 coherence,
// fast) and mirror sc0 sc1 (IF path, round-4 proven). Consumers poll the
// primary with sc0; sticky-escalate to the mirror after 200 failed polls.
// Wrong-coherence theory degrades to round-4 speed instead of hanging.
__global__ __launch_bounds__(512, 2) void gru_scan_kernel(
    const unsigned short* __restrict__ Whh,   // [3072][1024] bf16
    const float* __restrict__ gates,          // [T*B][3072] (= x-gates + b_ih)
    const float* __restrict__ bhh,            // [3072]
    unsigned short* __restrict__ hs,          // primary [T+1][B][H]; slice0 = 0
    unsigned short* __restrict__ hm,          // mirror  [T+1][B][H]; slice0 = 0
    int* __restrict__ claim) {                // [16]: [0..7] per-XCD, [8] winner
  __shared__ float ghp[2][8][3][16][17];      // [buf][wave][gate][batch][j] 52 KB
  __shared__ int slotLds;
  const int tid = threadIdx.x;

  if (tid == 0) {
    int xcd;
    asm volatile("s_getreg_b32 %0, hwreg(HW_REG_XCC_ID)" : "=s"(xcd));
    xcd &= 7;
    const int idx = __hip_atomic_fetch_add(&claim[xcd], 1, __ATOMIC_RELAXED,
                                           __HIP_MEMORY_SCOPE_AGENT);
    int slot = -1;
    if (idx < 64) {
      if (idx == 23) {                       // declare winner at 24 claims
        int expected = 0;
        __hip_atomic_compare_exchange_strong(&claim[8], &expected, xcd + 1,
                                             __ATOMIC_RELEASE, __ATOMIC_RELAXED,
                                             __HIP_MEMORY_SCOPE_AGENT);
      }
      int wnr;
      while ((wnr = __hip_atomic_load(&claim[8], __ATOMIC_ACQUIRE,
                                      __HIP_MEMORY_SCOPE_AGENT)) == 0) {
        __builtin_amdgcn_s_sleep(8);
      }
      if (wnr == xcd + 1) slot = idx;
    }
    slotLds = slot;
  }
  __syncthreads();
  const int g = slotLds;
  if (g < 0) return;                         // not a worker

  const int w = tid >> 6;                    // wave: K-slice [128w, 128w+128)
  const int l = tid & 63;
  const int lr = l & 15;
  const int lk8 = (l >> 4) * 8;
  const int j0 = g * 16;

  // ---- one-time: W_hh fragments into named registers (round-4 proven, 48 VGPR)
  const unsigned short* ap0 = Whh + (size_t)(j0 + lr) * H_ + w * 128 + lk8;
  const unsigned short* ap1 = ap0 + (size_t)H_ * H_;
  const unsigned short* ap2 = ap1 + (size_t)H_ * H_;
  i32x4 w00, w01, w02, w03, w10, w11, w12, w13, w20, w21, w22, w23;
  asm volatile(
      "global_load_dwordx4 %0,  %12, off\n\t"
      "global_load_dwordx4 %1,  %12, off offset:64\n\t"
      "global_load_dwordx4 %2,  %12, off offset:128\n\t"
      "global_load_dwordx4 %3,  %12, off offset:192\n\t"
      "global_load_dwordx4 %4,  %13, off\n\t"
      "global_load_dwordx4 %5,  %13, off offset:64\n\t"
      "global_load_dwordx4 %6,  %13, off offset:128\n\t"
      "global_load_dwordx4 %7,  %13, off offset:192\n\t"
      "global_load_dwordx4 %8,  %14, off\n\t"
      "global_load_dwordx4 %9,  %14, off offset:64\n\t"
      "global_load_dwordx4 %10, %14, off offset:128\n\t"
      "global_load_dwordx4 %11, %14, off offset:192\n\t"
      "s_waitcnt vmcnt(0)"
      : "=&v"(w00), "=&v"(w01), "=&v"(w02), "=&v"(w03),
        "=&v"(w10), "=&v"(w11), "=&v"(w12), "=&v"(w13),
        "=&v"(w20), "=&v"(w21), "=&v"(w22), "=&v"(w23)
      : "v"(ap0), "v"(ap1), "v"(ap2));
  const bf16x8 af00 = __builtin_bit_cast(bf16x8, w00);
  const bf16x8 af01 = __builtin_bit_cast(bf16x8, w01);
  const bf16x8 af02 = __builtin_bit_cast(bf16x8, w02);
  const bf16x8 af03 = __builtin_bit_cast(bf16x8, w03);
  const bf16x8 af10 = __builtin_bit_cast(bf16x8, w10);
  const bf16x8 af11 = __builtin_bit_cast(bf16x8, w11);
  const bf16x8 af12 = __builtin_bit_cast(bf16x8, w12);
  const bf16x8 af13 = __builtin_bit_cast(bf16x8, w13);
  const bf16x8 af20 = __builtin_bit_cast(bf16x8, w20);
  const bf16x8 af21 = __builtin_bit_cast(bf16x8, w21);
  const bf16x8 af22 = __builtin_bit_cast(bf16x8, w22);
  const bf16x8 af23 = __builtin_bit_cast(bf16x8, w23);

  const int jb = tid & 15;   // j within chunk   (valid for tid < 256)
  const int bb = tid >> 4;   // batch
  const float bhr = bhh[j0 + jb];
  const float bhz = bhh[H_ + j0 + jb];
  const float bhn = bhh[2 * H_ + j0 + jb];
  float hprev = 0.f;
  int esc = 0;               // sticky poll-escalation (wave-uniform)

  for (int t = 0; t < T_; ++t) {
    const int buf = t & 1;
    // x-gates for this step (independent of h; issued before the poll)
    float gxr = 0.f, gxz = 0.f, gxn = 0.f;
    if (tid < 256) {
      const size_t grow = ((size_t)t * B_ + bb) * G3_;
      gxr = gates[grow + j0 + jb];
      gxz = gates[grow + H_ + j0 + jb];
      gxn = gates[grow + 2 * H_ + j0 + jb];
    }

    // Poll-load h_t fragments until sentinel-free: primary sc0, mirror valve.
    const size_t hoff = (size_t)t * (B_ * H_) + (size_t)lr * H_ + w * 128 + lk8;
    const unsigned short* hp = hs + hoff;
    const unsigned short* hpm = hm + hoff;
    i32x4 u0, u1, u2, u3;
    int tries = 0;
    while (true) {
      if (!esc) {
        asm volatile(
            "global_load_dwordx4 %0, %4, off sc0\n\t"
            "global_load_dwordx4 %1, %4, off offset:64 sc0\n\t"
            "global_load_dwordx4 %2, %4, off offset:128 sc0\n\t"
            "global_load_dwordx4 %3, %4, off offset:192 sc0\n\t"
            "s_waitcnt vmcnt(0)"
            : "=&v"(u0), "=&v"(u1), "=&v"(u2), "=&v"(u3)
            : "v"(hp));
      } else {
        asm volatile(
            "global_load_dwordx4 %0, %4, off sc0 sc1\n\t"
            "global_load_dwordx4 %1, %4, off offset:64 sc0 sc1\n\t"
            "global_load_dwordx4 %2, %4, off offset:128 sc0 sc1\n\t"
            "global_load_dwordx4 %3, %4, off offset:192 sc0 sc1\n\t"
            "s_waitcnt vmcnt(0)"
            : "=&v"(u0), "=&v"(u1), "=&v"(u2), "=&v"(u3)
            : "v"(hpm));
      }
      const unsigned bad =
          sentmask(u0[0]) | sentmask(u0[1]) | sentmask(u0[2]) | sentmask(u0[3]) |
          sentmask(u1[0]) | sentmask(u1[1]) | sentmask(u1[2]) | sentmask(u1[3]) |
          sentmask(u2[0]) | sentmask(u2[1]) | sentmask(u2[2]) | sentmask(u2[3]) |
          sentmask(u3[0]) | sentmask(u3[1]) | sentmask(u3[2]) | sentmask(u3[3]);
      if (__ballot(bad == 0) == ~0ull) break;
      if (++tries > 200) esc = 1;            // sticky, wave-uniform
    }
    const bf16x8 hf0 = __builtin_bit_cast(bf16x8, u0);
    const bf16x8 hf1 = __builtin_bit_cast(bf16x8, u1);
    const bf16x8 hf2 = __builtin_bit_cast(bf16x8, u2);
    const bf16x8 hf3 = __builtin_bit_cast(bf16x8, u3);

    f32x4 C0 = (f32x4){0.f, 0.f, 0.f, 0.f}, C1 = C0, C2 = C0;
    C0 = __builtin_amdgcn_mfma_f32_16x16x32_bf16(af00, hf0, C0, 0, 0, 0);
    C1 = __builtin_amdgcn_mfma_f32_16x16x32_bf16(af10, hf0, C1, 0, 0, 0);
    C2 = __builtin_amdgcn_mfma_f32_16x16x32_bf16(af20, hf0, C2, 0, 0, 0);
    C0 = __builtin_amdgcn_mfma_f32_16x16x32_bf16(af01, hf1, C0, 0, 0, 0);
    C1 = __builtin_amdgcn_mfma_f32_16x16x32_bf16(af11, hf1, C1, 0, 0, 0);
    C2 = __builtin_amdgcn_mfma_f32_16x16x32_bf16(af21, hf1, C2, 0, 0, 0);
    C0 = __builtin_amdgcn_mfma_f32_16x16x32_bf16(af02, hf2, C0, 0, 0, 0);
    C1 = __builtin_amdgcn_mfma_f32_16x16x32_bf16(af12, hf2, C1, 0, 0, 0);
    C2 = __builtin_amdgcn_mfma_f32_16x16x32_bf16(af22, hf2, C2, 0, 0, 0);
    C0 = __builtin_amdgcn_mfma_f32_16x16x32_bf16(af03, hf3, C0, 0, 0, 0);
    C1 = __builtin_amdgcn_mfma_f32_16x16x32_bf16(af13, hf3, C1, 0, 0, 0);
    C2 = __builtin_amdgcn_mfma_f32_16x16x32_bf16(af23, hf3, C2, 0, 0, 0);

    const int rb = (l >> 4) * 4;
#pragma unroll
    for (int e = 0; e < 4; ++e) {
      ghp[buf][w][0][lr][rb + e] = C0[e];
      ghp[buf][w][1][lr][rb + e] = C1[e];
      ghp[buf][w][2][lr][rb + e] = C2[e];
    }
    __syncthreads();   // single barrier per step; buffer parity protects reuse

    if (tid < 256) {
      float sr = bhr, sz = bhz, sn = bhn;
#pragma unroll
      for (int w2 = 0; w2 < 8; ++w2) {
        sr += ghp[buf][w2][0][bb][jb];
        sz += ghp[buf][w2][1][bb][jb];
        sn += ghp[buf][w2][2][bb][jb];
      }
      const float r = 1.f / (1.f + __expf(-(gxr + sr)));
      const float z = 1.f / (1.f + __expf(-(gxz + sz)));
      const float xn = gxn + r * sn;
      const float n = 2.f / (1.f + __expf(-2.f * xn)) - 1.f;
      const float hnew = (1.f - z) * n + z * hprev;   // carry stays fp32
      hprev = hnew;
      const size_t soff = ((size_t)(t + 1) * B_ + bb) * H_ + j0 + jb;
      unsigned short* sp  = hs + soff;
      unsigned short* spm = hm + soff;
      const unsigned hv = (unsigned)f2bf(hnew);
      asm volatile("global_store_short %0, %2, off sc0\n\t"
                   "global_store_short %1, %2, off sc0 sc1"
                   :: "v"(sp), "v"(spm), "v"(hv) : "memory");
    }
  }
}

// ---------------------------------------------------------------- launch
extern "C" void kernel_launch(void* const* d_in, const int* in_sizes, int n_in,
                              void* d_out, int out_size, void* d_ws, size_t ws_size,
                              hipStream_t stream) {
  (void)in_sizes; (void)n_in; (void)out_size; (void)ws_size;
  const float* x    = (const float*)d_in[0];
  const float* w3   = (const float*)d_in[1];
  const float* b3   = (const float*)d_in[2];
  const float* w5   = (const float*)d_in[3];
  const float* b5   = (const float*)d_in[4];
  const float* w7   = (const float*)d_in[5];
  const float* b7   = (const float*)d_in[6];
  const float* wih  = (const float*)d_in[7];
  const float* whh  = (const float*)d_in[8];
  const float* bih  = (const float*)d_in[9];
  const float* bhh  = (const float*)d_in[10];
  // d_in[11..14]: attn_* — dead code (softmax over length-1 axis == 1)
  const float* fiw1 = (const float*)d_in[15];
  const float* fib1 = (const float*)d_in[16];
  const float* fiw2 = (const float*)d_in[17];
  const float* fib2 = (const float*)d_in[18];
  const float* lat  = (const float*)d_in[19];

  char* ws = (char*)d_ws;
  size_t off = 0;
  auto alloc = [&](size_t bytes) -> void* {
    void* p = ws + off;
    off += (bytes + 255) & ~(size_t)255;
    return p;
  };
  unsigned short* whh_bf  = (unsigned short*)alloc((size_t)G3_ * H_ * 2);
  unsigned short* wih_bf  = (unsigned short*)alloc((size_t)G3_ * KIN_ * 2);
  unsigned short* latT_bf = (unsigned short*)alloc((size_t)H_ * H_ * 2);
  unsigned short* fiw1_bf = (unsigned short*)alloc((size_t)H_ * H_ * 2);
  unsigned short* fiw2_bf = (unsigned short*)alloc((size_t)H_ * H_ * 2);
  unsigned short* feat_bf = (unsigned short*)alloc((size_t)B_ * T_ * KIN_ * 2);
  float*          gates   = (float*)alloc((size_t)B_ * T_ * G3_ * 4);
  unsigned short* hsbuf   = (unsigned short*)alloc((size_t)(T_ + 1) * B_ * H_ * 2);
  unsigned short* hmbuf   = (unsigned short*)alloc((size_t)(T_ + 1) * B_ * H_ * 2);
  unsigned short* inhib   = (unsigned short*)alloc((size_t)B_ * T_ * H_ * 2);
  unsigned short* y1      = (unsigned short*)alloc((size_t)B_ * T_ * H_ * 2);
  int*            claim   = (int*)alloc(16 * 4);

  prep_kernel<<<4096, 256, 0, stream>>>(whh, whh_bf, wih, wih_bf,
                                        fiw1, fiw1_bf, fiw2, fiw2_bf,
                                        lat, latT_bf, hsbuf, hmbuf,
                                        (float*)d_out + (size_t)B_ * T_ * H_,
                                        claim);

  conv_kernel<<<B_ * T_, 256, 0, stream>>>(x, w3, b3, w5, b5, w7, b7, feat_bf);

  {
    dim3 grid(G3_ / 128, (B_ * T_) / 128);
    gemm_kernel<0><<<grid, 256, 0, stream>>>(feat_bf, wih_bf, B_ * T_, G3_, KIN_,
                                             KIN_, KIN_, bih, gates, nullptr);
  }

  gru_scan_kernel<<<2048, 512, 0, stream>>>(whh_bf, gates, bhh, hsbuf, hmbuf, claim);

  const unsigned short* hs1 = hsbuf + (size_t)B_ * H_;   // slices 1..T
  {
    dim3 grid(H_ / 128, (B_ * T_) / 128);
    gemm_kernel<1><<<grid, 256, 0, stream>>>(hs1, latT_bf, B_ * T_, H_, H_,
                                             H_, H_, nullptr, nullptr, inhib);
    gemm_kernel<2><<<grid, 256, 0, stream>>>(inhib, fiw1_bf, B_ * T_, H_, H_,
                                             H_, H_, fib1, nullptr, y1);
    gemm_kernel<3><<<grid, 256, 0, stream>>>(y1, fiw2_bf, B_ * T_, H_, H_,
                                             H_, H_, fib2, (float*)d_out, nullptr);
  }
}

// Round 8
// 2249.947 us; speedup vs baseline: 1.3563x; 1.3563x over previous
//
#include <hip/hip_runtime.h>
#include <stdint.h>
#include <stddef.h>

#define B_   16
#define T_   256
#define L_   1024
#define H_   1024
#define G3_  3072
#define KIN_ 96

// NaN bf16 pattern: can never be produced by the GRU (|h| <= 1, finite arithmetic)
#define SENT_     0x7FC1
#define SENT_X2_  0x7FC17FC1u
#define ESC_TRIES 6

typedef __attribute__((ext_vector_type(8))) __bf16 bf16x8;
typedef __attribute__((ext_vector_type(4))) float  f32x4;
typedef __attribute__((ext_vector_type(4))) int    i32x4;

static __device__ __forceinline__ unsigned short f2bf(float x) {
  unsigned int u = __builtin_bit_cast(unsigned int, x);
  u += 0x7FFFu + ((u >> 16) & 1u);           // RNE
  return (unsigned short)(u >> 16);
}
static __device__ __forceinline__ float bf2f(unsigned short s) {
  unsigned int u = ((unsigned int)s) << 16;
  return __builtin_bit_cast(float, u);
}
// nonzero iff either 16-bit half of d equals the sentinel (exact SWAR detector)
static __device__ __forceinline__ unsigned sentmask(unsigned d) {
  const unsigned x = d ^ SENT_X2_;
  return (x - 0x00010001u) & ~x & 0x80008000u;
}

// ---------------------------------------------------------------- prep
// One fused kernel, plain stores (end-of-kernel L2 writeback publishes them):
// bf16 converts, lateral transpose, sentinel fills of hs + mirror, h0 zeros,
// attention-ones output.
__global__ void prep_kernel(
    const float* __restrict__ whh,  unsigned short* __restrict__ whh_bf,
    const float* __restrict__ wih,  unsigned short* __restrict__ wih_bf,
    const float* __restrict__ fiw1, unsigned short* __restrict__ fiw1_bf,
    const float* __restrict__ fiw2, unsigned short* __restrict__ fiw2_bf,
    const float* __restrict__ lat,  unsigned short* __restrict__ latT_bf,
    unsigned short* __restrict__ hsbuf, unsigned short* __restrict__ hmbuf,
    float* __restrict__ attn_out) {
  const int N0 = G3_ * H_;
  const int N1 = N0 + G3_ * KIN_;
  const int N2 = N1 + H_ * H_;
  const int N3 = N2 + H_ * H_;
  const int N4 = N3 + H_ * H_;             // lat transpose
  const int N5 = N4 + T_ * B_ * H_ / 2;    // hs sentinel (dword units)
  const int N6 = N5 + B_ * H_ / 2;         // hs h0 zero
  const int N7 = N6 + B_ * T_;             // attention ones
  const int N8 = N7 + T_ * B_ * H_ / 2;    // mirror sentinel
  const int N9 = N8 + B_ * H_ / 2;         // mirror h0 zero
  int i = blockIdx.x * 256 + threadIdx.x;
  const int stride = gridDim.x * 256;
  unsigned int* hs32 = (unsigned int*)hsbuf;
  unsigned int* hm32 = (unsigned int*)hmbuf;
  for (; i < N9; i += stride) {
    if (i < N0)      whh_bf[i] = f2bf(whh[i]);
    else if (i < N1) { const int j = i - N0; wih_bf[j]  = f2bf(wih[j]); }
    else if (i < N2) { const int j = i - N1; fiw1_bf[j] = f2bf(fiw1[j]); }
    else if (i < N3) { const int j = i - N2; fiw2_bf[j] = f2bf(fiw2[j]); }
    else if (i < N4) { const int j = i - N3; const int r = j >> 10, c = j & 1023;
                       latT_bf[(size_t)c * H_ + r] = f2bf(lat[j]); }
    else if (i < N5) { hs32[B_ * H_ / 2 + (i - N4)] = SENT_X2_; }
    else if (i < N6) { hs32[i - N5] = 0u; }
    else if (i < N7) { attn_out[i - N6] = 1.0f; }
    else if (i < N8) { hm32[B_ * H_ / 2 + (i - N7)] = SENT_X2_; }
    else             { hm32[i - N8] = 0u; }
  }
}

// ---------------------------------------------------------------- conv+pool
__global__ __launch_bounds__(256) void conv_kernel(
    const float* __restrict__ x,
    const float* __restrict__ w3, const float* __restrict__ b3,
    const float* __restrict__ w5, const float* __restrict__ b5,
    const float* __restrict__ w7, const float* __restrict__ b7,
    unsigned short* __restrict__ feat) {
  __shared__ float xpad[L_ + 8];
  __shared__ float wlds[96][8];
  __shared__ float blds[96];
  __shared__ float wmax[4][96];
  const int tid = threadIdx.x;
  const int rid = blockIdx.x;          // b*T + t
  const int b = rid >> 8;
  const int t = rid & 255;
  const float* xr = x + (size_t)rid * L_;
  for (int off = tid; off < L_; off += 256) xpad[off + 3] = xr[off];
  if (tid < 3) xpad[tid] = 0.f;
  if (tid >= 3 && tid < 8) xpad[L_ + tid] = 0.f;
  if (tid < 96) {
    const int f = tid;
    float wv[8];
#pragma unroll
    for (int k = 0; k < 8; ++k) wv[k] = 0.f;
    float bv;
    if (f < 32)      { for (int k = 0; k < 3; ++k) wv[k + 2] = w3[f * 3 + k]; bv = b3[f]; }
    else if (f < 64) { int ff = f - 32; for (int k = 0; k < 5; ++k) wv[k + 1] = w5[ff * 5 + k]; bv = b5[ff]; }
    else             { int ff = f - 64; for (int k = 0; k < 7; ++k) wv[k] = w7[ff * 7 + k]; bv = b7[ff]; }
#pragma unroll
    for (int k = 0; k < 8; ++k) wlds[f][k] = wv[k];
    blds[f] = bv;
  }
  __syncthreads();
  const int w = tid >> 6, lane = tid & 63;
  const int p0 = w * 256 + lane * 4;
  float xv[10];
#pragma unroll
  for (int i = 0; i < 10; ++i) xv[i] = xpad[p0 + i];
  for (int f = 0; f < 96; ++f) {
    float a0 = 0.f, a1 = 0.f, a2 = 0.f, a3 = 0.f;
#pragma unroll
    for (int k = 0; k < 7; ++k) {
      const float wk = wlds[f][k];
      a0 = fmaf(wk, xv[k],     a0);
      a1 = fmaf(wk, xv[k + 1], a1);
      a2 = fmaf(wk, xv[k + 2], a2);
      a3 = fmaf(wk, xv[k + 3], a3);
    }
    float m = fmaxf(fmaxf(a0, a1), fmaxf(a2, a3));
#pragma unroll
    for (int d = 1; d < 64; d <<= 1) m = fmaxf(m, __shfl_xor(m, d, 64));
    if (lane == 0) wmax[w][f] = m;
  }
  __syncthreads();
  if (tid < 96) {
    float m = fmaxf(fmaxf(wmax[0][tid], wmax[1][tid]),
                    fmaxf(wmax[2][tid], wmax[3][tid]));
    m += blds[tid];
    m = m > 0.f ? m : 0.f;
    feat[(size_t)(t * B_ + b) * KIN_ + tid] = f2bf(m);   // row = t*B + b
  }
}

// ---------------------------------------------------------------- GEMM
// C[M,N] = A[M,K] * B[N,K]^T  (both bf16, row-major). 128x128 tile, BK=32,
// 4 waves, double-buffered LDS, padded stride 40.
template <int EP>
__global__ __launch_bounds__(256) void gemm_kernel(
    const unsigned short* __restrict__ A,
    const unsigned short* __restrict__ Bm,
    int M, int N, int K, int lda, int ldb,
    const float* __restrict__ bias,
    float* __restrict__ outF,
    unsigned short* __restrict__ outB) {
  __shared__ __align__(16) unsigned short As[2][128 * 40];
  __shared__ __align__(16) unsigned short Bs[2][128 * 40];
  const int tid = threadIdx.x;
  const int n0 = blockIdx.x * 128;
  const int m0 = blockIdx.y * 128;
  const int w = tid >> 6;
  const int l = tid & 63;
  const int lr = l & 15;
  const int lk = (l >> 4) * 8;
  const int srow = tid >> 2;
  const int skc = (tid & 3) * 8;

  f32x4 acc[2][8];
#pragma unroll
  for (int i = 0; i < 2; ++i)
#pragma unroll
    for (int j = 0; j < 8; ++j) acc[i][j] = (f32x4){0.f, 0.f, 0.f, 0.f};

  const int NK = K >> 5;
  const unsigned short* Aptr  = A  + (size_t)(m0 + srow)      * lda + skc;
  const unsigned short* Aptr2 = A  + (size_t)(m0 + 64 + srow) * lda + skc;
  const unsigned short* Bptr  = Bm + (size_t)(n0 + srow)      * ldb + skc;
  const unsigned short* Bptr2 = Bm + (size_t)(n0 + 64 + srow) * ldb + skc;

  i32x4 ar0 = *(const i32x4*)(Aptr);
  i32x4 ar1 = *(const i32x4*)(Aptr2);
  i32x4 br0 = *(const i32x4*)(Bptr);
  i32x4 br1 = *(const i32x4*)(Bptr2);
  *(i32x4*)&As[0][srow * 40 + skc]        = ar0;
  *(i32x4*)&As[0][(64 + srow) * 40 + skc] = ar1;
  *(i32x4*)&Bs[0][srow * 40 + skc]        = br0;
  *(i32x4*)&Bs[0][(64 + srow) * 40 + skc] = br1;
  __syncthreads();

  for (int kk = 0; kk < NK; ++kk) {
    const int cur = kk & 1;
    if (kk + 1 < NK) {
      const int ko = (kk + 1) << 5;
      ar0 = *(const i32x4*)(Aptr  + ko);
      ar1 = *(const i32x4*)(Aptr2 + ko);
      br0 = *(const i32x4*)(Bptr  + ko);
      br1 = *(const i32x4*)(Bptr2 + ko);
    }
    const bf16x8 a0 = *(const bf16x8*)&As[cur][(w * 32 + lr) * 40 + lk];
    const bf16x8 a1 = *(const bf16x8*)&As[cur][(w * 32 + 16 + lr) * 40 + lk];
#pragma unroll
    for (int nt = 0; nt < 8; ++nt) {
      const bf16x8 bb = *(const bf16x8*)&Bs[cur][(nt * 16 + lr) * 40 + lk];
      acc[0][nt] = __builtin_amdgcn_mfma_f32_16x16x32_bf16(a0, bb, acc[0][nt], 0, 0, 0);
      acc[1][nt] = __builtin_amdgcn_mfma_f32_16x16x32_bf16(a1, bb, acc[1][nt], 0, 0, 0);
    }
    __syncthreads();
    if (kk + 1 < NK) {
      const int nxt = cur ^ 1;
      *(i32x4*)&As[nxt][srow * 40 + skc]        = ar0;
      *(i32x4*)&As[nxt][(64 + srow) * 40 + skc] = ar1;
      *(i32x4*)&Bs[nxt][srow * 40 + skc]        = br0;
      *(i32x4*)&Bs[nxt][(64 + srow) * 40 + skc] = br1;
    }
    __syncthreads();
  }

#pragma unroll
  for (int mt = 0; mt < 2; ++mt) {
#pragma unroll
    for (int nt = 0; nt < 8; ++nt) {
      const f32x4 v = acc[mt][nt];
      const int gcol = n0 + nt * 16 + lr;
#pragma unroll
      for (int e = 0; e < 4; ++e) {
        const int grow = m0 + w * 32 + mt * 16 + (l >> 4) * 4 + e;
        const float val = v[e];
        if (EP == 0) {
          outF[(size_t)grow * N + gcol] = val + bias[gcol];
        } else if (EP == 1) {
          const float hsv = bf2f(A[(size_t)grow * lda + gcol]);
          outB[(size_t)grow * N + gcol] = f2bf(hsv - fmaxf(val, 0.f));
        } else if (EP == 2) {
          outB[(size_t)grow * N + gcol] = f2bf(fmaxf(val + bias[gcol], 0.f));
        } else {
          const int tt = grow >> 4;   // row = t*B + b
          const int bb2 = grow & 15;
          outF[((size_t)bb2 * T_ + tt) * H_ + gcol] = val + bias[gcol];
        }
      }
    }
  }
}

// ---------------------------------------------------------------- GRU scan
// Round-4 proven structure (64 workers x 512 thr, 16 cols/WG, 12 pinned
// weight quads, single barrier, sentinel data-signal) with static XCD
// placement attempt: workers are bids 0,8,16,...,504 of a 512-WG grid (the
// default round-robin bid->XCD mapping would co-locate them on one XCD;
// heuristic only, never required for correctness). Producers store h twice:
// primary sc0 (shared-L2 fast path) + mirror sc0 sc1 (IF, round-4 proven).
// Consumers poll primary sc0; sticky-escalate to the mirror after only
// ESC_TRIES failed polls — a stale-L2 wrong-placement costs ~2k cycles once
// per wave, then runs at round-4 speed. No hang possible.
__global__ __launch_bounds__(512, 2) void gru_scan_kernel(
    const unsigned short* __restrict__ Whh,   // [3072][1024] bf16
    const float* __restrict__ gates,          // [T*B][3072] (= x-gates + b_ih)
    const float* __restrict__ bhh,            // [3072]
    unsigned short* __restrict__ hs,          // primary [T+1][B][H]; slice0 = 0
    unsigned short* __restrict__ hm) {        // mirror  [T+1][B][H]; slice0 = 0
  const int bid = blockIdx.x;
  if (bid & 7) return;                       // keep bids 0 mod 8 (one per XCD slot)
  const int g = bid >> 3;                    // worker id 0..63
  const int tid = threadIdx.x;

  __shared__ float ghp[2][8][3][16][17];     // [buf][wave][gate][batch][j] 52 KB
  const int w = tid >> 6;                    // wave: K-slice [128w, 128w+128)
  const int l = tid & 63;
  const int lr = l & 15;
  const int lk8 = (l >> 4) * 8;
  const int j0 = g * 16;

  // ---- one-time: W_hh fragments into named registers (round-4 proven, 48 VGPR)
  const unsigned short* ap0 = Whh + (size_t)(j0 + lr) * H_ + w * 128 + lk8;
  const unsigned short* ap1 = ap0 + (size_t)H_ * H_;
  const unsigned short* ap2 = ap1 + (size_t)H_ * H_;
  i32x4 w00, w01, w02, w03, w10, w11, w12, w13, w20, w21, w22, w23;
  asm volatile(
      "global_load_dwordx4 %0,  %12, off\n\t"
      "global_load_dwordx4 %1,  %12, off offset:64\n\t"
      "global_load_dwordx4 %2,  %12, off offset:128\n\t"
      "global_load_dwordx4 %3,  %12, off offset:192\n\t"
      "global_load_dwordx4 %4,  %13, off\n\t"
      "global_load_dwordx4 %5,  %13, off offset:64\n\t"
      "global_load_dwordx4 %6,  %13, off offset:128\n\t"
      "global_load_dwordx4 %7,  %13, off offset:192\n\t"
      "global_load_dwordx4 %8,  %14, off\n\t"
      "global_load_dwordx4 %9,  %14, off offset:64\n\t"
      "global_load_dwordx4 %10, %14, off offset:128\n\t"
      "global_load_dwordx4 %11, %14, off offset:192\n\t"
      "s_waitcnt vmcnt(0)"
      : "=&v"(w00), "=&v"(w01), "=&v"(w02), "=&v"(w03),
        "=&v"(w10), "=&v"(w11), "=&v"(w12), "=&v"(w13),
        "=&v"(w20), "=&v"(w21), "=&v"(w22), "=&v"(w23)
      : "v"(ap0), "v"(ap1), "v"(ap2));
  const bf16x8 af00 = __builtin_bit_cast(bf16x8, w00);
  const bf16x8 af01 = __builtin_bit_cast(bf16x8, w01);
  const bf16x8 af02 = __builtin_bit_cast(bf16x8, w02);
  const bf16x8 af03 = __builtin_bit_cast(bf16x8, w03);
  const bf16x8 af10 = __builtin_bit_cast(bf16x8, w10);
  const bf16x8 af11 = __builtin_bit_cast(bf16x8, w11);
  const bf16x8 af12 = __builtin_bit_cast(bf16x8, w12);
  const bf16x8 af13 = __builtin_bit_cast(bf16x8, w13);
  const bf16x8 af20 = __builtin_bit_cast(bf16x8, w20);
  const bf16x8 af21 = __builtin_bit_cast(bf16x8, w21);
  const bf16x8 af22 = __builtin_bit_cast(bf16x8, w22);
  const bf16x8 af23 = __builtin_bit_cast(bf16x8, w23);

  const int jb = tid & 15;   // j within chunk   (valid for tid < 256)
  const int bb = tid >> 4;   // batch
  const float bhr = bhh[j0 + jb];
  const float bhz = bhh[H_ + j0 + jb];
  const float bhn = bhh[2 * H_ + j0 + jb];
  float hprev = 0.f;
  int esc = 0;               // sticky poll-escalation (wave-uniform)

  for (int t = 0; t < T_; ++t) {
    const int buf = t & 1;
    // x-gates for this step (independent of h; issued before the poll)
    float gxr = 0.f, gxz = 0.f, gxn = 0.f;
    if (tid < 256) {
      const size_t grow = ((size_t)t * B_ + bb) * G3_;
      gxr = gates[grow + j0 + jb];
      gxz = gates[grow + H_ + j0 + jb];
      gxn = gates[grow + 2 * H_ + j0 + jb];
    }

    // Poll-load h_t fragments until sentinel-free: primary sc0, tight valve.
    const size_t hoff = (size_t)t * (B_ * H_) + (size_t)lr * H_ + w * 128 + lk8;
    const unsigned short* hp  = hs + hoff;
    const unsigned short* hpm = hm + hoff;
    i32x4 u0, u1, u2, u3;
    int tries = 0;
    while (true) {
      if (!esc) {
        asm volatile(
            "global_load_dwordx4 %0, %4, off sc0\n\t"
            "global_load_dwordx4 %1, %4, off offset:64 sc0\n\t"
            "global_load_dwordx4 %2, %4, off offset:128 sc0\n\t"
            "global_load_dwordx4 %3, %4, off offset:192 sc0\n\t"
            "s_waitcnt vmcnt(0)"
            : "=&v"(u0), "=&v"(u1), "=&v"(u2), "=&v"(u3)
            : "v"(hp));
      } else {
        asm volatile(
            "global_load_dwordx4 %0, %4, off sc0 sc1\n\t"
            "global_load_dwordx4 %1, %4, off offset:64 sc0 sc1\n\t"
            "global_load_dwordx4 %2, %4, off offset:128 sc0 sc1\n\t"
            "global_load_dwordx4 %3, %4, off offset:192 sc0 sc1\n\t"
            "s_waitcnt vmcnt(0)"
            : "=&v"(u0), "=&v"(u1), "=&v"(u2), "=&v"(u3)
            : "v"(hpm));
      }
      const unsigned bad =
          sentmask(u0[0]) | sentmask(u0[1]) | sentmask(u0[2]) | sentmask(u0[3]) |
          sentmask(u1[0]) | sentmask(u1[1]) | sentmask(u1[2]) | sentmask(u1[3]) |
          sentmask(u2[0]) | sentmask(u2[1]) | sentmask(u2[2]) | sentmask(u2[3]) |
          sentmask(u3[0]) | sentmask(u3[1]) | sentmask(u3[2]) | sentmask(u3[3]);
      if (__ballot(bad == 0) == ~0ull) break;
      if (++tries > ESC_TRIES) esc = 1;      // tight, sticky, wave-uniform
    }
    const bf16x8 hf0 = __builtin_bit_cast(bf16x8, u0);
    const bf16x8 hf1 = __builtin_bit_cast(bf16x8, u1);
    const bf16x8 hf2 = __builtin_bit_cast(bf16x8, u2);
    const bf16x8 hf3 = __builtin_bit_cast(bf16x8, u3);

    f32x4 C0 = (f32x4){0.f, 0.f, 0.f, 0.f}, C1 = C0, C2 = C0;
    C0 = __builtin_amdgcn_mfma_f32_16x16x32_bf16(af00, hf0, C0, 0, 0, 0);
    C1 = __builtin_amdgcn_mfma_f32_16x16x32_bf16(af10, hf0, C1, 0, 0, 0);
    C2 = __builtin_amdgcn_mfma_f32_16x16x32_bf16(af20, hf0, C2, 0, 0, 0);
    C0 = __builtin_amdgcn_mfma_f32_16x16x32_bf16(af01, hf1, C0, 0, 0, 0);
    C1 = __builtin_amdgcn_mfma_f32_16x16x32_bf16(af11, hf1, C1, 0, 0, 0);
    C2 = __builtin_amdgcn_mfma_f32_16x16x32_bf16(af21, hf1, C2, 0, 0, 0);
    C0 = __builtin_amdgcn_mfma_f32_16x16x32_bf16(af02, hf2, C0, 0, 0, 0);
    C1 = __builtin_amdgcn_mfma_f32_16x16x32_bf16(af12, hf2, C1, 0, 0, 0);
    C2 = __builtin_amdgcn_mfma_f32_16x16x32_bf16(af22, hf2, C2, 0, 0, 0);
    C0 = __builtin_amdgcn_mfma_f32_16x16x32_bf16(af03, hf3, C0, 0, 0, 0);
    C1 = __builtin_amdgcn_mfma_f32_16x16x32_bf16(af13, hf3, C1, 0, 0, 0);
    C2 = __builtin_amdgcn_mfma_f32_16x16x32_bf16(af23, hf3, C2, 0, 0, 0);

    const int rb = (l >> 4) * 4;
#pragma unroll
    for (int e = 0; e < 4; ++e) {
      ghp[buf][w][0][lr][rb + e] = C0[e];
      ghp[buf][w][1][lr][rb + e] = C1[e];
      ghp[buf][w][2][lr][rb + e] = C2[e];
    }
    __syncthreads();   // single barrier per step; buffer parity protects reuse

    if (tid < 256) {
      float sr = bhr, sz = bhz, sn = bhn;
#pragma unroll
      for (int w2 = 0; w2 < 8; ++w2) {
        sr += ghp[buf][w2][0][bb][jb];
        sz += ghp[buf][w2][1][bb][jb];
        sn += ghp[buf][w2][2][bb][jb];
      }
      const float r = 1.f / (1.f + __expf(-(gxr + sr)));
      const float z = 1.f / (1.f + __expf(-(gxz + sz)));
      const float xn = gxn + r * sn;
      const float n = 2.f / (1.f + __expf(-2.f * xn)) - 1.f;
      const float hnew = (1.f - z) * n + z * hprev;   // carry stays fp32
      hprev = hnew;
      const size_t soff = ((size_t)(t + 1) * B_ + bb) * H_ + j0 + jb;
      unsigned short* sp  = hs + soff;
      unsigned short* spm = hm + soff;
      const unsigned hv = (unsigned)f2bf(hnew);
      asm volatile("global_store_short %0, %2, off sc0\n\t"
                   "global_store_short %1, %2, off sc0 sc1"
                   :: "v"(sp), "v"(spm), "v"(hv) : "memory");
    }
  }
}

// ---------------------------------------------------------------- launch
extern "C" void kernel_launch(void* const* d_in, const int* in_sizes, int n_in,
                              void* d_out, int out_size, void* d_ws, size_t ws_size,
                              hipStream_t stream) {
  (void)in_sizes; (void)n_in; (void)out_size; (void)ws_size;
  const float* x    = (const float*)d_in[0];
  const float* w3   = (const float*)d_in[1];
  const float* b3   = (const float*)d_in[2];
  const float* w5   = (const float*)d_in[3];
  const float* b5   = (const float*)d_in[4];
  const float* w7   = (const float*)d_in[5];
  const float* b7   = (const float*)d_in[6];
  const float* wih  = (const float*)d_in[7];
  const float* whh  = (const float*)d_in[8];
  const float* bih  = (const float*)d_in[9];
  const float* bhh  = (const float*)d_in[10];
  // d_in[11..14]: attn_* — dead code (softmax over length-1 axis == 1)
  const float* fiw1 = (const float*)d_in[15];
  const float* fib1 = (const float*)d_in[16];
  const float* fiw2 = (const float*)d_in[17];
  const float* fib2 = (const float*)d_in[18];
  const float* lat  = (const float*)d_in[19];

  char* ws = (char*)d_ws;
  size_t off = 0;
  auto alloc = [&](size_t bytes) -> void* {
    void* p = ws + off;
    off += (bytes + 255) & ~(size_t)255;
    return p;
  };
  unsigned short* whh_bf  = (unsigned short*)alloc((size_t)G3_ * H_ * 2);
  unsigned short* wih_bf  = (unsigned short*)alloc((size_t)G3_ * KIN_ * 2);
  unsigned short* latT_bf = (unsigned short*)alloc((size_t)H_ * H_ * 2);
  unsigned short* fiw1_bf = (unsigned short*)alloc((size_t)H_ * H_ * 2);
  unsigned short* fiw2_bf = (unsigned short*)alloc((size_t)H_ * H_ * 2);
  unsigned short* feat_bf = (unsigned short*)alloc((size_t)B_ * T_ * KIN_ * 2);
  float*          gates   = (float*)alloc((size_t)B_ * T_ * G3_ * 4);
  unsigned short* hsbuf   = (unsigned short*)alloc((size_t)(T_ + 1) * B_ * H_ * 2);
  unsigned short* hmbuf   = (unsigned short*)alloc((size_t)(T_ + 1) * B_ * H_ * 2);
  unsigned short* inhib   = (unsigned short*)alloc((size_t)B_ * T_ * H_ * 2);
  unsigned short* y1      = (unsigned short*)alloc((size_t)B_ * T_ * H_ * 2);

  prep_kernel<<<4096, 256, 0, stream>>>(whh, whh_bf, wih, wih_bf,
                                        fiw1, fiw1_bf, fiw2, fiw2_bf,
                                        lat, latT_bf, hsbuf, hmbuf,
                                        (float*)d_out + (size_t)B_ * T_ * H_);

  conv_kernel<<<B_ * T_, 256, 0, stream>>>(x, w3, b3, w5, b5, w7, b7, feat_bf);

  {
    dim3 grid(G3_ / 128, (B_ * T_) / 128);
    gemm_kernel<0><<<grid, 256, 0, stream>>>(feat_bf, wih_bf, B_ * T_, G3_, KIN_,
                                             KIN_, KIN_, bih, gates, nullptr);
  }

  gru_scan_kernel<<<512, 512, 0, stream>>>(whh_bf, gates, bhh, hsbuf, hmbuf);

  const unsigned short* hs1 = hsbuf + (size_t)B_ * H_;   // slices 1..T
  {
    dim3 grid(H_ / 128, (B_ * T_) / 128);
    gemm_kernel<1><<<grid, 256, 0, stream>>>(hs1, latT_bf, B_ * T_, H_, H_,
                                             H_, H_, nullptr, nullptr, inhib);
    gemm_kernel<2><<<grid, 256, 0, stream>>>(inhib, fiw1_bf, B_ * T_, H_, H_,
                                             H_, H_, fib1, nullptr, y1);
    gemm_kernel<3><<<grid, 256, 0, stream>>>(y1, fiw2_bf, B_ * T_, H_, H_,
                                             H_, H_, fib2, (float*)d_out, nullptr);
  }
}

// Round 9
// 1063.610 us; speedup vs baseline: 2.8692x; 2.1154x over previous
//
#include <hip/hip_runtime.h>
#include <stdint.h>
#include <stddef.h>

#define B_   16
#define T_   256
#define L_   1024
#define H_   1024
#define G3_  3072
#define KIN_ 96

// NaN bf16 pattern: can never be produced by the GRU (|h| <= 1, finite arithmetic)
#define SENT_     0x7FC1
#define SENT_X2_  0x7FC17FC1u

typedef __attribute__((ext_vector_type(8))) __bf16 bf16x8;
typedef __attribute__((ext_vector_type(4))) float  f32x4;
typedef __attribute__((ext_vector_type(4))) int    i32x4;

static __device__ __forceinline__ unsigned short f2bf(float x) {
  unsigned int u = __builtin_bit_cast(unsigned int, x);
  u += 0x7FFFu + ((u >> 16) & 1u);           // RNE
  return (unsigned short)(u >> 16);
}
static __device__ __forceinline__ float bf2f(unsigned short s) {
  unsigned int u = ((unsigned int)s) << 16;
  return __builtin_bit_cast(float, u);
}
// nonzero iff either 16-bit half of d equals the sentinel (exact SWAR detector)
static __device__ __forceinline__ unsigned sentmask(unsigned d) {
  const unsigned x = d ^ SENT_X2_;
  return (x - 0x00010001u) & ~x & 0x80008000u;
}

// ---------------------------------------------------------------- prep
// One fused kernel, plain stores (end-of-kernel L2 writeback publishes them):
// bf16 converts, lateral transpose, hs sentinel fill, h0 zero, attention-ones.
__global__ void prep_kernel(
    const float* __restrict__ whh,  unsigned short* __restrict__ whh_bf,
    const float* __restrict__ wih,  unsigned short* __restrict__ wih_bf,
    const float* __restrict__ fiw1, unsigned short* __restrict__ fiw1_bf,
    const float* __restrict__ fiw2, unsigned short* __restrict__ fiw2_bf,
    const float* __restrict__ lat,  unsigned short* __restrict__ latT_bf,
    unsigned short* __restrict__ hsbuf, float* __restrict__ attn_out) {
  const int N0 = G3_ * H_;
  const int N1 = N0 + G3_ * KIN_;
  const int N2 = N1 + H_ * H_;
  const int N3 = N2 + H_ * H_;
  const int N4 = N3 + H_ * H_;             // lat transpose
  const int N5 = N4 + T_ * B_ * H_ / 2;    // hs sentinel (dword units)
  const int N6 = N5 + B_ * H_ / 2;         // hs h0 zero
  const int N7 = N6 + B_ * T_;             // attention ones
  int i = blockIdx.x * 256 + threadIdx.x;
  const int stride = gridDim.x * 256;
  unsigned int* hs32 = (unsigned int*)hsbuf;
  for (; i < N7; i += stride) {
    if (i < N0)      whh_bf[i] = f2bf(whh[i]);
    else if (i < N1) { const int j = i - N0; wih_bf[j]  = f2bf(wih[j]); }
    else if (i < N2) { const int j = i - N1; fiw1_bf[j] = f2bf(fiw1[j]); }
    else if (i < N3) { const int j = i - N2; fiw2_bf[j] = f2bf(fiw2[j]); }
    else if (i < N4) { const int j = i - N3; const int r = j >> 10, c = j & 1023;
                       latT_bf[(size_t)c * H_ + r] = f2bf(lat[j]); }
    else if (i < N5) { hs32[B_ * H_ / 2 + (i - N4)] = SENT_X2_; }
    else if (i < N6) { hs32[i - N5] = 0u; }
    else             { attn_out[i - N6] = 1.0f; }
  }
}

// ---------------------------------------------------------------- conv+pool
__global__ __launch_bounds__(256) void conv_kernel(
    const float* __restrict__ x,
    const float* __restrict__ w3, const float* __restrict__ b3,
    const float* __restrict__ w5, const float* __restrict__ b5,
    const float* __restrict__ w7, const float* __restrict__ b7,
    unsigned short* __restrict__ feat) {
  __shared__ float xpad[L_ + 8];
  __shared__ float wlds[96][8];
  __shared__ float blds[96];
  __shared__ float wmax[4][96];
  const int tid = threadIdx.x;
  const int rid = blockIdx.x;          // b*T + t
  const int b = rid >> 8;
  const int t = rid & 255;
  const float* xr = x + (size_t)rid * L_;
  for (int off = tid; off < L_; off += 256) xpad[off + 3] = xr[off];
  if (tid < 3) xpad[tid] = 0.f;
  if (tid >= 3 && tid < 8) xpad[L_ + tid] = 0.f;
  if (tid < 96) {
    const int f = tid;
    float wv[8];
#pragma unroll
    for (int k = 0; k < 8; ++k) wv[k] = 0.f;
    float bv;
    if (f < 32)      { for (int k = 0; k < 3; ++k) wv[k + 2] = w3[f * 3 + k]; bv = b3[f]; }
    else if (f < 64) { int ff = f - 32; for (int k = 0; k < 5; ++k) wv[k + 1] = w5[ff * 5 + k]; bv = b5[ff]; }
    else             { int ff = f - 64; for (int k = 0; k < 7; ++k) wv[k] = w7[ff * 7 + k]; bv = b7[ff]; }
#pragma unroll
    for (int k = 0; k < 8; ++k) wlds[f][k] = wv[k];
    blds[f] = bv;
  }
  __syncthreads();
  const int w = tid >> 6, lane = tid & 63;
  const int p0 = w * 256 + lane * 4;
  float xv[10];
#pragma unroll
  for (int i = 0; i < 10; ++i) xv[i] = xpad[p0 + i];
  for (int f = 0; f < 96; ++f) {
    float a0 = 0.f, a1 = 0.f, a2 = 0.f, a3 = 0.f;
#pragma unroll
    for (int k = 0; k < 7; ++k) {
      const float wk = wlds[f][k];
      a0 = fmaf(wk, xv[k],     a0);
      a1 = fmaf(wk, xv[k + 1], a1);
      a2 = fmaf(wk, xv[k + 2], a2);
      a3 = fmaf(wk, xv[k + 3], a3);
    }
    float m = fmaxf(fmaxf(a0, a1), fmaxf(a2, a3));
#pragma unroll
    for (int d = 1; d < 64; d <<= 1) m = fmaxf(m, __shfl_xor(m, d, 64));
    if (lane == 0) wmax[w][f] = m;
  }
  __syncthreads();
  if (tid < 96) {
    float m = fmaxf(fmaxf(wmax[0][tid], wmax[1][tid]),
                    fmaxf(wmax[2][tid], wmax[3][tid]));
    m += blds[tid];
    m = m > 0.f ? m : 0.f;
    feat[(size_t)(t * B_ + b) * KIN_ + tid] = f2bf(m);   // row = t*B + b
  }
}

// ---------------------------------------------------------------- GEMM
// C[M,N] = A[M,K] * B[N,K]^T  (both bf16, row-major). 128x128 tile, BK=32,
// 4 waves, double-buffered LDS, padded stride 40.
template <int EP>
__global__ __launch_bounds__(256) void gemm_kernel(
    const unsigned short* __restrict__ A,
    const unsigned short* __restrict__ Bm,
    int M, int N, int K, int lda, int ldb,
    const float* __restrict__ bias,
    float* __restrict__ outF,
    unsigned short* __restrict__ outB) {
  __shared__ __align__(16) unsigned short As[2][128 * 40];
  __shared__ __align__(16) unsigned short Bs[2][128 * 40];
  const int tid = threadIdx.x;
  const int n0 = blockIdx.x * 128;
  const int m0 = blockIdx.y * 128;
  const int w = tid >> 6;
  const int l = tid & 63;
  const int lr = l & 15;
  const int lk = (l >> 4) * 8;
  const int srow = tid >> 2;
  const int skc = (tid & 3) * 8;

  f32x4 acc[2][8];
#pragma unroll
  for (int i = 0; i < 2; ++i)
#pragma unroll
    for (int j = 0; j < 8; ++j) acc[i][j] = (f32x4){0.f, 0.f, 0.f, 0.f};

  const int NK = K >> 5;
  const unsigned short* Aptr  = A  + (size_t)(m0 + srow)      * lda + skc;
  const unsigned short* Aptr2 = A  + (size_t)(m0 + 64 + srow) * lda + skc;
  const unsigned short* Bptr  = Bm + (size_t)(n0 + srow)      * ldb + skc;
  const unsigned short* Bptr2 = Bm + (size_t)(n0 + 64 + srow) * ldb + skc;

  i32x4 ar0 = *(const i32x4*)(Aptr);
  i32x4 ar1 = *(const i32x4*)(Aptr2);
  i32x4 br0 = *(const i32x4*)(Bptr);
  i32x4 br1 = *(const i32x4*)(Bptr2);
  *(i32x4*)&As[0][srow * 40 + skc]        = ar0;
  *(i32x4*)&As[0][(64 + srow) * 40 + skc] = ar1;
  *(i32x4*)&Bs[0][srow * 40 + skc]        = br0;
  *(i32x4*)&Bs[0][(64 + srow) * 40 + skc] = br1;
  __syncthreads();

  for (int kk = 0; kk < NK; ++kk) {
    const int cur = kk & 1;
    if (kk + 1 < NK) {
      const int ko = (kk + 1) << 5;
      ar0 = *(const i32x4*)(Aptr  + ko);
      ar1 = *(const i32x4*)(Aptr2 + ko);
      br0 = *(const i32x4*)(Bptr  + ko);
      br1 = *(const i32x4*)(Bptr2 + ko);
    }
    const bf16x8 a0 = *(const bf16x8*)&As[cur][(w * 32 + lr) * 40 + lk];
    const bf16x8 a1 = *(const bf16x8*)&As[cur][(w * 32 + 16 + lr) * 40 + lk];
#pragma unroll
    for (int nt = 0; nt < 8; ++nt) {
      const bf16x8 bb = *(const bf16x8*)&Bs[cur][(nt * 16 + lr) * 40 + lk];
      acc[0][nt] = __builtin_amdgcn_mfma_f32_16x16x32_bf16(a0, bb, acc[0][nt], 0, 0, 0);
      acc[1][nt] = __builtin_amdgcn_mfma_f32_16x16x32_bf16(a1, bb, acc[1][nt], 0, 0, 0);
    }
    __syncthreads();
    if (kk + 1 < NK) {
      const int nxt = cur ^ 1;
      *(i32x4*)&As[nxt][srow * 40 + skc]        = ar0;
      *(i32x4*)&As[nxt][(64 + srow) * 40 + skc] = ar1;
      *(i32x4*)&Bs[nxt][srow * 40 + skc]        = br0;
      *(i32x4*)&Bs[nxt][(64 + srow) * 40 + skc] = br1;
    }
    __syncthreads();
  }

#pragma unroll
  for (int mt = 0; mt < 2; ++mt) {
#pragma unroll
    for (int nt = 0; nt < 8; ++nt) {
      const f32x4 v = acc[mt][nt];
      const int gcol = n0 + nt * 16 + lr;
#pragma unroll
      for (int e = 0; e < 4; ++e) {
        const int grow = m0 + w * 32 + mt * 16 + (l >> 4) * 4 + e;
        const float val = v[e];
        if (EP == 0) {
          outF[(size_t)grow * N + gcol] = val + bias[gcol];
        } else if (EP == 1) {
          const float hsv = bf2f(A[(size_t)grow * lda + gcol]);
          outB[(size_t)grow * N + gcol] = f2bf(hsv - fmaxf(val, 0.f));
        } else if (EP == 2) {
          outB[(size_t)grow * N + gcol] = f2bf(fmaxf(val + bias[gcol], 0.f));
        } else {
          const int tt = grow >> 4;   // row = t*B + b
          const int bb2 = grow & 15;
          outF[((size_t)bb2 * T_ + tt) * H_ + gcol] = val + bias[gcol];
        }
      }
    }
  }
}

// ---------------------------------------------------------------- GRU scan
// Round-4 proven protocol (64 WGs spread over the chip, 512 thr, 16 cols/WG,
// 12 pinned weight quads, single barrier, sentinel data-signal, sc0 sc1
// everywhere) with ONE change: the publish is shuffle-packed in registers and
// stored as 32 coalesced 16B dwordx4 units per WG (vs 256 scattered 2B
// stores). Each consumer 16B fragment == exactly one producer store unit
// (8-short aligned), landing atomically -> sentinel check on dwords 0+3 only,
// and no partially-arrived-unit re-polls.
__global__ __launch_bounds__(512, 2) void gru_scan_kernel(
    const unsigned short* __restrict__ Whh,   // [3072][1024] bf16
    const float* __restrict__ gates,          // [T*B][3072] (= x-gates + b_ih)
    const float* __restrict__ bhh,            // [3072]
    unsigned short* __restrict__ hs) {        // [T+1][B][H]; slice0 = 0
  const int g = blockIdx.x;                   // worker id 0..63
  const int tid = threadIdx.x;

  __shared__ float ghp[2][8][3][16][17];      // [buf][wave][gate][batch][j] 52 KB
  const int w = tid >> 6;                     // wave: K-slice [128w, 128w+128)
  const int l = tid & 63;
  const int lr = l & 15;
  const int lk8 = (l >> 4) * 8;
  const int j0 = g * 16;

  // ---- one-time: W_hh fragments into named registers (round-4 proven, 48 VGPR)
  const unsigned short* ap0 = Whh + (size_t)(j0 + lr) * H_ + w * 128 + lk8;
  const unsigned short* ap1 = ap0 + (size_t)H_ * H_;
  const unsigned short* ap2 = ap1 + (size_t)H_ * H_;
  i32x4 w00, w01, w02, w03, w10, w11, w12, w13, w20, w21, w22, w23;
  asm volatile(
      "global_load_dwordx4 %0,  %12, off\n\t"
      "global_load_dwordx4 %1,  %12, off offset:64\n\t"
      "global_load_dwordx4 %2,  %12, off offset:128\n\t"
      "global_load_dwordx4 %3,  %12, off offset:192\n\t"
      "global_load_dwordx4 %4,  %13, off\n\t"
      "global_load_dwordx4 %5,  %13, off offset:64\n\t"
      "global_load_dwordx4 %6,  %13, off offset:128\n\t"
      "global_load_dwordx4 %7,  %13, off offset:192\n\t"
      "global_load_dwordx4 %8,  %14, off\n\t"
      "global_load_dwordx4 %9,  %14, off offset:64\n\t"
      "global_load_dwordx4 %10, %14, off offset:128\n\t"
      "global_load_dwordx4 %11, %14, off offset:192\n\t"
      "s_waitcnt vmcnt(0)"
      : "=&v"(w00), "=&v"(w01), "=&v"(w02), "=&v"(w03),
        "=&v"(w10), "=&v"(w11), "=&v"(w12), "=&v"(w13),
        "=&v"(w20), "=&v"(w21), "=&v"(w22), "=&v"(w23)
      : "v"(ap0), "v"(ap1), "v"(ap2));
  const bf16x8 af00 = __builtin_bit_cast(bf16x8, w00);
  const bf16x8 af01 = __builtin_bit_cast(bf16x8, w01);
  const bf16x8 af02 = __builtin_bit_cast(bf16x8, w02);
  const bf16x8 af03 = __builtin_bit_cast(bf16x8, w03);
  const bf16x8 af10 = __builtin_bit_cast(bf16x8, w10);
  const bf16x8 af11 = __builtin_bit_cast(bf16x8, w11);
  const bf16x8 af12 = __builtin_bit_cast(bf16x8, w12);
  const bf16x8 af13 = __builtin_bit_cast(bf16x8, w13);
  const bf16x8 af20 = __builtin_bit_cast(bf16x8, w20);
  const bf16x8 af21 = __builtin_bit_cast(bf16x8, w21);
  const bf16x8 af22 = __builtin_bit_cast(bf16x8, w22);
  const bf16x8 af23 = __builtin_bit_cast(bf16x8, w23);

  const int jb = tid & 15;   // j within chunk   (valid for tid < 256)
  const int bb = tid >> 4;   // batch
  const float bhr = bhh[j0 + jb];
  const float bhz = bhh[H_ + j0 + jb];
  const float bhn = bhh[2 * H_ + j0 + jb];
  float hprev = 0.f;

  for (int t = 0; t < T_; ++t) {
    const int buf = t & 1;
    // x-gates for this step (independent of h; issued before the poll)
    float gxr = 0.f, gxz = 0.f, gxn = 0.f;
    if (tid < 256) {
      const size_t grow = ((size_t)t * B_ + bb) * G3_;
      gxr = gates[grow + j0 + jb];
      gxz = gates[grow + H_ + j0 + jb];
      gxn = gates[grow + 2 * H_ + j0 + jb];
    }

    // Poll-load h_t fragments through the coherence point until sentinel-free.
    // Each fragment is one atomically-stored 16B unit -> check dwords 0 and 3.
    const unsigned short* hp = hs + (size_t)t * (B_ * H_) +
                               (size_t)lr * H_ + w * 128 + lk8;
    i32x4 u0, u1, u2, u3;
    while (true) {
      asm volatile(
          "global_load_dwordx4 %0, %4, off sc0 sc1\n\t"
          "global_load_dwordx4 %1, %4, off offset:64 sc0 sc1\n\t"
          "global_load_dwordx4 %2, %4, off offset:128 sc0 sc1\n\t"
          "global_load_dwordx4 %3, %4, off offset:192 sc0 sc1\n\t"
          "s_waitcnt vmcnt(0)"
          : "=&v"(u0), "=&v"(u1), "=&v"(u2), "=&v"(u3)
          : "v"(hp)
          : "memory");
      const unsigned bad = sentmask(u0[0]) | sentmask(u0[3]) |
                           sentmask(u1[0]) | sentmask(u1[3]) |
                           sentmask(u2[0]) | sentmask(u2[3]) |
                           sentmask(u3[0]) | sentmask(u3[3]);
      if (__ballot(bad == 0) == ~0ull) break;
    }
    const bf16x8 hf0 = __builtin_bit_cast(bf16x8, u0);
    const bf16x8 hf1 = __builtin_bit_cast(bf16x8, u1);
    const bf16x8 hf2 = __builtin_bit_cast(bf16x8, u2);
    const bf16x8 hf3 = __builtin_bit_cast(bf16x8, u3);

    f32x4 C0 = (f32x4){0.f, 0.f, 0.f, 0.f}, C1 = C0, C2 = C0;
    C0 = __builtin_amdgcn_mfma_f32_16x16x32_bf16(af00, hf0, C0, 0, 0, 0);
    C1 = __builtin_amdgcn_mfma_f32_16x16x32_bf16(af10, hf0, C1, 0, 0, 0);
    C2 = __builtin_amdgcn_mfma_f32_16x16x32_bf16(af20, hf0, C2, 0, 0, 0);
    C0 = __builtin_amdgcn_mfma_f32_16x16x32_bf16(af01, hf1, C0, 0, 0, 0);
    C1 = __builtin_amdgcn_mfma_f32_16x16x32_bf16(af11, hf1, C1, 0, 0, 0);
    C2 = __builtin_amdgcn_mfma_f32_16x16x32_bf16(af21, hf1, C2, 0, 0, 0);
    C0 = __builtin_amdgcn_mfma_f32_16x16x32_bf16(af02, hf2, C0, 0, 0, 0);
    C1 = __builtin_amdgcn_mfma_f32_16x16x32_bf16(af12, hf2, C1, 0, 0, 0);
    C2 = __builtin_amdgcn_mfma_f32_16x16x32_bf16(af22, hf2, C2, 0, 0, 0);
    C0 = __builtin_amdgcn_mfma_f32_16x16x32_bf16(af03, hf3, C0, 0, 0, 0);
    C1 = __builtin_amdgcn_mfma_f32_16x16x32_bf16(af13, hf3, C1, 0, 0, 0);
    C2 = __builtin_amdgcn_mfma_f32_16x16x32_bf16(af23, hf3, C2, 0, 0, 0);

    const int rb = (l >> 4) * 4;
#pragma unroll
    for (int e = 0; e < 4; ++e) {
      ghp[buf][w][0][lr][rb + e] = C0[e];
      ghp[buf][w][1][lr][rb + e] = C1[e];
      ghp[buf][w][2][lr][rb + e] = C2[e];
    }
    __syncthreads();   // single barrier per step; buffer parity protects reuse

    if (tid < 256) {
      float sr = bhr, sz = bhz, sn = bhn;
#pragma unroll
      for (int w2 = 0; w2 < 8; ++w2) {
        sr += ghp[buf][w2][0][bb][jb];
        sz += ghp[buf][w2][1][bb][jb];
        sn += ghp[buf][w2][2][bb][jb];
      }
      const float r = 1.f / (1.f + __expf(-(gxr + sr)));
      const float z = 1.f / (1.f + __expf(-(gxz + sz)));
      const float xn = gxn + r * sn;
      const float n = 2.f / (1.f + __expf(-2.f * xn)) - 1.f;
      const float hnew = (1.f - z) * n + z * hprev;   // carry stays fp32
      hprev = hnew;

      // shuffle-pack 8 consecutive cols into one lane; 16B coalesced publish
      const unsigned hv = (unsigned)f2bf(hnew);
      const int base = l & ~7;
      const unsigned s0 = __shfl(hv, base + 0, 64);
      const unsigned s1 = __shfl(hv, base + 1, 64);
      const unsigned s2 = __shfl(hv, base + 2, 64);
      const unsigned s3 = __shfl(hv, base + 3, 64);
      const unsigned s4 = __shfl(hv, base + 4, 64);
      const unsigned s5 = __shfl(hv, base + 5, 64);
      const unsigned s6 = __shfl(hv, base + 6, 64);
      const unsigned s7 = __shfl(hv, base + 7, 64);
      i32x4 pk;
      pk[0] = (int)(s0 | (s1 << 16));
      pk[1] = (int)(s2 | (s3 << 16));
      pk[2] = (int)(s4 | (s5 << 16));
      pk[3] = (int)(s6 | (s7 << 16));
      if ((l & 7) == 0) {
        unsigned short* sp = hs + ((size_t)(t + 1) * B_ + bb) * H_ + j0 + (l & 15);
        asm volatile("global_store_dwordx4 %0, %1, off sc0 sc1"
                     :: "v"(sp), "v"(pk) : "memory");
      }
    }
  }
}

// ---------------------------------------------------------------- launch
extern "C" void kernel_launch(void* const* d_in, const int* in_sizes, int n_in,
                              void* d_out, int out_size, void* d_ws, size_t ws_size,
                              hipStream_t stream) {
  (void)in_sizes; (void)n_in; (void)out_size; (void)ws_size;
  const float* x    = (const float*)d_in[0];
  const float* w3   = (const float*)d_in[1];
  const float* b3   = (const float*)d_in[2];
  const float* w5   = (const float*)d_in[3];
  const float* b5   = (const float*)d_in[4];
  const float* w7   = (const float*)d_in[5];
  const float* b7   = (const float*)d_in[6];
  const float* wih  = (const float*)d_in[7];
  const float* whh  = (const float*)d_in[8];
  const float* bih  = (const float*)d_in[9];
  const float* bhh  = (const float*)d_in[10];
  // d_in[11..14]: attn_* — dead code (softmax over length-1 axis == 1)
  const float* fiw1 = (const float*)d_in[15];
  const float* fib1 = (const float*)d_in[16];
  const float* fiw2 = (const float*)d_in[17];
  const float* fib2 = (const float*)d_in[18];
  const float* lat  = (const float*)d_in[19];

  char* ws = (char*)d_ws;
  size_t off = 0;
  auto alloc = [&](size_t bytes) -> void* {
    void* p = ws + off;
    off += (bytes + 255) & ~(size_t)255;
    return p;
  };
  unsigned short* whh_bf  = (unsigned short*)alloc((size_t)G3_ * H_ * 2);
  unsigned short* wih_bf  = (unsigned short*)alloc((size_t)G3_ * KIN_ * 2);
  unsigned short* latT_bf = (unsigned short*)alloc((size_t)H_ * H_ * 2);
  unsigned short* fiw1_bf = (unsigned short*)alloc((size_t)H_ * H_ * 2);
  unsigned short* fiw2_bf = (unsigned short*)alloc((size_t)H_ * H_ * 2);
  unsigned short* feat_bf = (unsigned short*)alloc((size_t)B_ * T_ * KIN_ * 2);
  float*          gates   = (float*)alloc((size_t)B_ * T_ * G3_ * 4);
  unsigned short* hsbuf   = (unsigned short*)alloc((size_t)(T_ + 1) * B_ * H_ * 2);
  unsigned short* inhib   = (unsigned short*)alloc((size_t)B_ * T_ * H_ * 2);
  unsigned short* y1      = (unsigned short*)alloc((size_t)B_ * T_ * H_ * 2);

  prep_kernel<<<4096, 256, 0, stream>>>(whh, whh_bf, wih, wih_bf,
                                        fiw1, fiw1_bf, fiw2, fiw2_bf,
                                        lat, latT_bf, hsbuf,
                                        (float*)d_out + (size_t)B_ * T_ * H_);

  conv_kernel<<<B_ * T_, 256, 0, stream>>>(x, w3, b3, w5, b5, w7, b7, feat_bf);

  {
    dim3 grid(G3_ / 128, (B_ * T_) / 128);
    gemm_kernel<0><<<grid, 256, 0, stream>>>(feat_bf, wih_bf, B_ * T_, G3_, KIN_,
                                             KIN_, KIN_, bih, gates, nullptr);
  }

  gru_scan_kernel<<<64, 512, 0, stream>>>(whh_bf, gates, bhh, hsbuf);

  const unsigned short* hs1 = hsbuf + (size_t)B_ * H_;   // slices 1..T
  {
    dim3 grid(H_ / 128, (B_ * T_) / 128);
    gemm_kernel<1><<<grid, 256, 0, stream>>>(hs1, latT_bf, B_ * T_, H_, H_,
                                             H_, H_, nullptr, nullptr, inhib);
    gemm_kernel<2><<<grid, 256, 0, stream>>>(inhib, fiw1_bf, B_ * T_, H_, H_,
                                             H_, H_, fib1, nullptr, y1);
    gemm_kernel<3><<<grid, 256, 0, stream>>>(y1, fiw2_bf, B_ * T_, H_, H_,
                                             H_, H_, fib2, (float*)d_out, nullptr);
  }
}